// Round 2
// baseline (715.014 us; speedup 1.0000x reference)
//
#include <hip/hip_runtime.h>
#include <hip/hip_bf16.h>
#include <cstdint>

#define BB 8
#define CC 16
#define DD 32
#define HH 112
#define WW 112
#define TT 16        // D_OUT
#define HID 256
#define OUTN 128
#define INSZ 784     // C*7*7

__device__ __forceinline__ float bf16lo(uint32_t u) { return __uint_as_float(u << 16); }
__device__ __forceinline__ float bf16hi(uint32_t u) { return __uint_as_float(u & 0xffff0000u); }
__device__ __forceinline__ float bf16s(uint16_t u)  { return __uint_as_float(((uint32_t)u) << 16); }

__device__ __forceinline__ uint16_t f32_to_bf16_rne(float f) {
    uint32_t u = __float_as_uint(f);
    return (uint16_t)((u + 0x7fffu + ((u >> 16) & 1u)) >> 16);
}

// ---------------------------------------------------------------------------
// Dtype detector: bf16 stream -> all uint16 decode to sane exponents;
// f32 stream -> even-index uint16 are mantissa halves, ~44% weird exponents.
// flag = 1 means inputs are float32, 0 means bfloat16.
// ---------------------------------------------------------------------------
__global__ __launch_bounds__(256) void detect_kernel(const uint16_t* __restrict__ x,
                                                     int* __restrict__ flag) {
    __shared__ int cnt;
    if (threadIdx.x == 0) cnt = 0;
    __syncthreads();
    int local = 0;
    for (int i = threadIdx.x; i < 8192; i += 256) {
        uint32_t e = (x[i] >> 7) & 0xFFu;   // bf16 exponent field
        if (e == 0u || e >= 0x90u) local++;
    }
    atomicAdd(&cnt, local);
    __syncthreads();
    if (threadIdx.x == 0) *flag = (cnt > 400) ? 1 : 0;
}

// ---------------------------------------------------------------------------
// Pool: x (B,C,D,H,W) -> seq (T, B, INSZ) f32.
// Composed pool = mean over (2,16,16)=512 elems (equal-size mean of means).
// One block per (b,c,t): reads a fully CONTIGUOUS 2*112*112 region.
// ---------------------------------------------------------------------------
__global__ __launch_bounds__(256) void pool_kernel(const void* __restrict__ xv,
                                                   float* __restrict__ seq,
                                                   const int* __restrict__ flag) {
    const int isf32 = *flag;
    int gid = blockIdx.x;                 // 2048 blocks
    int t = gid & 15, c = (gid >> 4) & 15, b = gid >> 8;
    long base = (long)(((b * CC + c) * DD) + t * 2) * (HH * WW);  // element offset
    __shared__ float bins[49];
    int tid = threadIdx.x;
    if (tid < 49) bins[tid] = 0.0f;
    __syncthreads();
    if (!isf32) {
        const uint4* p = reinterpret_cast<const uint4*>((const uint16_t*)xv + base);
        // 2*112*112 / 8 = 3136 vec8 chunks; each chunk lies in exactly one bin.
        for (int m = tid; m < 3136; m += 256) {
            int m2 = (m >= 1568) ? m - 1568 : m;   // drop d'
            int h  = m2 / 14;                      // 14 chunks per row of 112
            int wq = m2 - h * 14;
            int bin = (h >> 4) * 7 + (wq >> 1);
            uint4 v = p[m];
            float s = bf16lo(v.x) + bf16hi(v.x) + bf16lo(v.y) + bf16hi(v.y)
                    + bf16lo(v.z) + bf16hi(v.z) + bf16lo(v.w) + bf16hi(v.w);
            atomicAdd(&bins[bin], s);
        }
    } else {
        const float4* p = reinterpret_cast<const float4*>((const float*)xv + base);
        // 2*112*112 / 4 = 6272 vec4 chunks (28 per row); one bin per chunk.
        for (int m = tid; m < 6272; m += 256) {
            int m2 = (m >= 3136) ? m - 3136 : m;
            int h  = m2 / 28;
            int wq = m2 - h * 28;
            int bin = (h >> 4) * 7 + (wq >> 2);
            float4 v = p[m];
            atomicAdd(&bins[bin], v.x + v.y + v.z + v.w);
        }
    }
    __syncthreads();
    if (tid < 49) {
        seq[(long)(t * BB + b) * INSZ + c * 49 + tid] = bins[tid] * (1.0f / 512.0f);
    }
}

// ---------------------------------------------------------------------------
// W_hh -> f32 (so the sequential GRU inner loop is pure f32 FMA)
// ---------------------------------------------------------------------------
__global__ __launch_bounds__(256) void cvt_whh(const void* __restrict__ whh,
                                               float* __restrict__ out,
                                               const int* __restrict__ flag) {
    const int isf32 = *flag;
    int i = blockIdx.x * 256 + threadIdx.x;   // grid 768 -> 196608 exactly
    out[i] = isf32 ? ((const float*)whh)[i] : bf16s(((const uint16_t*)whh)[i]);
}

// ---------------------------------------------------------------------------
// gi[t,b,j] = b_ih[j] + dot(seq[t,b,:], W_ih[j,:])  -- parallel over all t
// grid 128 = (t*8+b), 768 threads = one per gate row j.
// ---------------------------------------------------------------------------
__global__ __launch_bounds__(768) void gi_kernel(const float* __restrict__ seq,
                                                 const void* __restrict__ Wih,
                                                 const void* __restrict__ bih,
                                                 float* __restrict__ gi,
                                                 const int* __restrict__ flag) {
    const int isf32 = *flag;
    int tb = blockIdx.x;
    int j  = threadIdx.x;
    __shared__ __align__(16) float s_in[INSZ];
    const float* srow = seq + (long)tb * INSZ;
    for (int i = j; i < INSZ; i += 768) s_in[i] = srow[i];
    __syncthreads();
    float acc;
    if (!isf32) {
        const uint4* wr = reinterpret_cast<const uint4*>((const uint16_t*)Wih + (long)j * INSZ);
        acc = bf16s(((const uint16_t*)bih)[j]);
        #pragma unroll 7
        for (int k = 0; k < 98; k++) {
            uint4 v = wr[k];
            const float* sp = &s_in[k * 8];
            acc += bf16lo(v.x) * sp[0] + bf16hi(v.x) * sp[1]
                 + bf16lo(v.y) * sp[2] + bf16hi(v.y) * sp[3]
                 + bf16lo(v.z) * sp[4] + bf16hi(v.z) * sp[5]
                 + bf16lo(v.w) * sp[6] + bf16hi(v.w) * sp[7];
        }
    } else {
        const float4* wr = reinterpret_cast<const float4*>((const float*)Wih + (long)j * INSZ);
        acc = ((const float*)bih)[j];
        #pragma unroll 7
        for (int k = 0; k < 196; k++) {
            float4 v = wr[k];
            const float* sp = &s_in[k * 4];
            acc += v.x * sp[0] + v.y * sp[1] + v.z * sp[2] + v.w * sp[3];
        }
    }
    gi[(long)tb * 768 + j] = acc;
}

// ---------------------------------------------------------------------------
// Sequential GRU: one block per batch. 768 threads: thread j computes gh row j
// each step; threads j<256 apply gates. Epilogue: j<128 -> out = h@W_out^T+b.
// ---------------------------------------------------------------------------
__global__ __launch_bounds__(768) void gru_kernel(const float* __restrict__ gi,
                                                  const float* __restrict__ whh32,
                                                  const void* __restrict__ bhh,
                                                  const void* __restrict__ Wout,
                                                  const void* __restrict__ bout,
                                                  void* __restrict__ out,
                                                  const int* __restrict__ flag) {
    const int isf32 = *flag;
    int b = blockIdx.x;
    int j = threadIdx.x;
    __shared__ __align__(16) float h_s[HID];
    __shared__ __align__(16) float g_s[768];
    if (j < HID) h_s[j] = 0.0f;
    float bh = isf32 ? ((const float*)bhh)[j] : bf16s(((const uint16_t*)bhh)[j]);
    const float4* wr = reinterpret_cast<const float4*>(whh32 + (long)j * HID);
    __syncthreads();
    for (int t = 0; t < TT; t++) {
        float acc = bh;
        const float4* hp = reinterpret_cast<const float4*>(h_s);
        #pragma unroll 8
        for (int k = 0; k < 64; k++) {
            float4 w  = wr[k];
            float4 hv = hp[k];                 // LDS broadcast
            acc += w.x * hv.x + w.y * hv.y + w.z * hv.z + w.w * hv.w;
        }
        g_s[j] = acc;
        __syncthreads();                       // g_s ready; dot phase done reading h_s
        if (j < HID) {
            const float* gp = gi + (long)(t * BB + b) * 768;
            float r = 1.0f / (1.0f + __expf(-(gp[j]       + g_s[j])));
            float z = 1.0f / (1.0f + __expf(-(gp[j + 256] + g_s[j + 256])));
            float npre = gp[j + 512] + r * g_s[j + 512];
            float n = 2.0f / (1.0f + __expf(-2.0f * npre)) - 1.0f;  // tanh
            h_s[j] = (1.0f - z) * n + z * h_s[j];
        }
        __syncthreads();                       // h_s ready for next step
    }
    if (j < OUTN) {
        float acc = isf32 ? ((const float*)bout)[j] : bf16s(((const uint16_t*)bout)[j]);
        if (!isf32) {
            const uint4* wo = reinterpret_cast<const uint4*>((const uint16_t*)Wout + (long)j * HID);
            #pragma unroll
            for (int k = 0; k < 32; k++) {
                uint4 v = wo[k];
                const float* hp2 = &h_s[k * 8];
                acc += bf16lo(v.x) * hp2[0] + bf16hi(v.x) * hp2[1]
                     + bf16lo(v.y) * hp2[2] + bf16hi(v.y) * hp2[3]
                     + bf16lo(v.z) * hp2[4] + bf16hi(v.z) * hp2[5]
                     + bf16lo(v.w) * hp2[6] + bf16hi(v.w) * hp2[7];
            }
            ((uint16_t*)out)[b * OUTN + j] = f32_to_bf16_rne(acc);
        } else {
            const float4* wo = reinterpret_cast<const float4*>((const float*)Wout + (long)j * HID);
            #pragma unroll
            for (int k = 0; k < 64; k++) {
                float4 v = wo[k];
                const float* hp2 = &h_s[k * 4];
                acc += v.x * hp2[0] + v.y * hp2[1] + v.z * hp2[2] + v.w * hp2[3];
            }
            ((float*)out)[b * OUTN + j] = acc;
        }
    }
}

extern "C" void kernel_launch(void* const* d_in, const int* in_sizes, int n_in,
                              void* d_out, int out_size, void* d_ws, size_t ws_size,
                              hipStream_t stream) {
    const void* x    = d_in[0];  // 8*16*32*112*112
    const void* Wih  = d_in[1];  // 768*784
    const void* Whh  = d_in[2];  // 768*256
    const void* bih  = d_in[3];  // 768
    const void* bhh  = d_in[4];  // 768
    const void* Wout = d_in[5];  // 128*256
    const void* bout = d_in[6];  // 128

    char* ws = (char*)d_ws;
    int*   flagp = (int*)ws;                                  // 16 B slot
    float* seq   = (float*)(ws + 16);                         // 100352 f32 = 401408 B
    float* gi    = (float*)(ws + 16 + 401408);                //  98304 f32 = 393216 B
    float* whh32 = (float*)(ws + 16 + 401408 + 393216);       // 196608 f32 = 786432 B

    detect_kernel<<<1, 256, 0, stream>>>((const uint16_t*)x, flagp);
    pool_kernel<<<2048, 256, 0, stream>>>(x, seq, flagp);
    cvt_whh<<<768, 256, 0, stream>>>(Whh, whh32, flagp);
    gi_kernel<<<128, 768, 0, stream>>>(seq, Wih, bih, gi, flagp);
    gru_kernel<<<8, 768, 0, stream>>>(gi, whh32, bhh, Wout, bout, d_out, flagp);
}

// Round 5
// 462.580 us; speedup vs baseline: 1.5457x; 1.5457x over previous
//
#include <hip/hip_runtime.h>
#include <hip/hip_bf16.h>
#include <cstdint>

#define BB 8
#define CC 16
#define DD 32
#define HH 112
#define WW 112
#define TT 16        // D_OUT
#define HID 256
#define OUTN 128
#define INSZ 784     // C*7*7

__device__ __forceinline__ float bf16lo(uint32_t u) { return __uint_as_float(u << 16); }
__device__ __forceinline__ float bf16hi(uint32_t u) { return __uint_as_float(u & 0xffff0000u); }
__device__ __forceinline__ float bf16s(uint16_t u)  { return __uint_as_float(((uint32_t)u) << 16); }

__device__ __forceinline__ uint16_t f32_to_bf16_rne(float f) {
    uint32_t u = __float_as_uint(f);
    return (uint16_t)((u + 0x7fffu + ((u >> 16) & 1u)) >> 16);
}

// ---------------------------------------------------------------------------
// Dtype detector (PROVEN in round 2): bf16 stream -> sane exponents everywhere;
// f32 stream -> even-index u16 are mantissa halves, ~44% weird exponents.
// flag = 1 means float32 inputs, 0 means bfloat16.
// ---------------------------------------------------------------------------
__global__ __launch_bounds__(256) void detect_kernel(const uint16_t* __restrict__ x,
                                                     int* __restrict__ flag) {
    __shared__ int cnt;
    if (threadIdx.x == 0) cnt = 0;
    __syncthreads();
    int local = 0;
    for (int i = threadIdx.x; i < 8192; i += 256) {
        uint32_t e = (x[i] >> 7) & 0xFFu;
        if (e == 0u || e >= 0x90u) local++;
    }
    atomicAdd(&cnt, local);
    __syncthreads();
    if (threadIdx.x == 0) *flag = (cnt > 400) ? 1 : 0;
}

// ---------------------------------------------------------------------------
// Pool: x (B,C,D,H,W) -> seq (T,B,INSZ) f32. Mean over (2,16,16)=512 elems.
// One block per (b,c,t): contiguous 2*112*112 read; per-vec-chunk sums in
// LDS (no atomics); 49 threads reduce.
// ---------------------------------------------------------------------------
__global__ __launch_bounds__(256) void pool_kernel(const void* __restrict__ xv,
                                                   float* __restrict__ seq,
                                                   const int* __restrict__ flag) {
    const int isf32 = *flag;
    int gid = blockIdx.x;                 // 2048 blocks
    int t = gid & 15, c = (gid >> 4) & 15, b = gid >> 8;
    long base = (long)(((b * CC + c) * DD) + t * 2) * (HH * WW);  // elem offset
    __shared__ float chunk[6272];
    int tid = threadIdx.x;
    float s = 0.0f;
    if (!isf32) {
        // bf16: 3136 vec8 chunks (14 per row of 112)
        const uint4* p = reinterpret_cast<const uint4*>((const uint16_t*)xv + base);
        for (int m = tid; m < 3136; m += 256) {
            uint4 v = p[m];
            chunk[m] = bf16lo(v.x) + bf16hi(v.x) + bf16lo(v.y) + bf16hi(v.y)
                     + bf16lo(v.z) + bf16hi(v.z) + bf16lo(v.w) + bf16hi(v.w);
        }
        __syncthreads();
        if (tid < 49) {
            int h2 = tid / 7, w2 = tid - h2 * 7;
            #pragma unroll
            for (int d = 0; d < 2; d++)
                for (int hh = 0; hh < 16; hh++) {
                    int row = d * 1568 + (h2 * 16 + hh) * 14 + w2 * 2;
                    s += chunk[row] + chunk[row + 1];
                }
        }
    } else {
        // f32: 6272 vec4 chunks (28 per row of 112), 3136 per d-slice
        const float4* p = reinterpret_cast<const float4*>((const float*)xv + base);
        for (int m = tid; m < 6272; m += 256) {
            float4 v = p[m];
            chunk[m] = v.x + v.y + v.z + v.w;
        }
        __syncthreads();
        if (tid < 49) {
            int h2 = tid / 7, w2 = tid - h2 * 7;
            #pragma unroll
            for (int d = 0; d < 2; d++)
                for (int hh = 0; hh < 16; hh++) {
                    int row = d * 3136 + (h2 * 16 + hh) * 28 + w2 * 4;
                    s += chunk[row] + chunk[row + 1] + chunk[row + 2] + chunk[row + 3];
                }
        }
    }
    if (tid < 49) {
        seq[(long)(t * BB + b) * INSZ + c * 49 + tid] = s * (1.0f / 512.0f);
    }
}

// ---------------------------------------------------------------------------
// Pack-convert-transpose a k-slice of W (R rows, K cols) to f32 WT[kl][R]:
// WT[kl*R + r] = (float)W[r][K0+kl], kl in [0,KK). Reads coalesced along k.
// ---------------------------------------------------------------------------
template <int R, int K, int K0, int KK>
__global__ __launch_bounds__(256) void packT_kernel(const void* __restrict__ W,
                                                    float* __restrict__ WT,
                                                    const int* __restrict__ flag) {
    const int isf32 = *flag;
    int g = blockIdx.x * 256 + threadIdx.x;       // g < R*KK exactly
    int r = g / KK, kl = g - r * KK;
    float v = isf32 ? ((const float*)W)[(long)r * K + K0 + kl]
                    : bf16s(((const uint16_t*)W)[(long)r * K + K0 + kl]);
    WT[(long)kl * R + r] = v;
}

// ---------------------------------------------------------------------------
// gi[t,b,j] (+)= dot(seq[t,b,K0:K0+KK], W_ih[j,K0:K0+KK]) (+ b_ih on pass 0)
// grid 128 = (t*8+b), 768 threads = gate row j. WT reads lane-coalesced.
// ---------------------------------------------------------------------------
template <int K0, int KK>
__global__ __launch_bounds__(768) void gi_kernel(const float* __restrict__ seq,
                                                 const float* __restrict__ wT,
                                                 const void* __restrict__ bih,
                                                 float* __restrict__ gi,
                                                 const int* __restrict__ flag) {
    const int isf32 = *flag;
    int tb = blockIdx.x;
    int j  = threadIdx.x;
    __shared__ __align__(16) float s_in[INSZ];
    const float* srow = seq + (long)tb * INSZ;
    for (int i = j; i < INSZ; i += 768) s_in[i] = srow[i];
    __syncthreads();
    float acc;
    if (K0 == 0) acc = isf32 ? ((const float*)bih)[j] : bf16s(((const uint16_t*)bih)[j]);
    else         acc = gi[(long)tb * 768 + j];
    const float* wp = wT + j;
    #pragma unroll 14
    for (int kl = 0; kl < KK; kl++) {
        acc += wp[(long)kl * 768] * s_in[K0 + kl];   // coalesced + LDS broadcast
    }
    gi[(long)tb * 768 + j] = acc;
}

// ---------------------------------------------------------------------------
// Sequential GRU: one block per batch. Thread j computes gh row j per step
// (coalesced whhT f32 reads); j<256 applies gates; j<128 final linear.
// ---------------------------------------------------------------------------
__global__ __launch_bounds__(768) void gru_kernel(const float* __restrict__ gi,
                                                  const float* __restrict__ whhT,
                                                  const void* __restrict__ bhh,
                                                  const void* __restrict__ Wout,
                                                  const void* __restrict__ bout,
                                                  void* __restrict__ out,
                                                  const int* __restrict__ flag) {
    const int isf32 = *flag;
    int b = blockIdx.x;
    int j = threadIdx.x;
    __shared__ __align__(16) float h_s[HID];
    __shared__ __align__(16) float g_s[768];
    if (j < HID) h_s[j] = 0.0f;
    float bh = isf32 ? ((const float*)bhh)[j] : bf16s(((const uint16_t*)bhh)[j]);
    const float* wp = whhT + j;
    __syncthreads();
    for (int t = 0; t < TT; t++) {
        float acc = bh;
        #pragma unroll 16
        for (int k = 0; k < HID; k++) {
            acc += wp[(long)k * 768] * h_s[k];       // coalesced + LDS broadcast
        }
        g_s[j] = acc;
        __syncthreads();                  // g_s ready; dots done reading h_s
        if (j < HID) {
            const float* gp = gi + (long)(t * BB + b) * 768;
            float r = 1.0f / (1.0f + __expf(-(gp[j]       + g_s[j])));
            float z = 1.0f / (1.0f + __expf(-(gp[j + 256] + g_s[j + 256])));
            float npre = gp[j + 512] + r * g_s[j + 512];
            float n = 2.0f / (1.0f + __expf(-2.0f * npre)) - 1.0f;  // tanh
            h_s[j] = (1.0f - z) * n + z * h_s[j];
        }
        __syncthreads();                  // h_s ready for next step
    }
    if (j < OUTN) {
        float acc = isf32 ? ((const float*)bout)[j] : bf16s(((const uint16_t*)bout)[j]);
        if (!isf32) {
            const uint4* wo = reinterpret_cast<const uint4*>((const uint16_t*)Wout + (long)j * HID);
            #pragma unroll
            for (int k = 0; k < 32; k++) {
                uint4 v = wo[k];
                const float* hp2 = &h_s[k * 8];
                acc += bf16lo(v.x) * hp2[0] + bf16hi(v.x) * hp2[1]
                     + bf16lo(v.y) * hp2[2] + bf16hi(v.y) * hp2[3]
                     + bf16lo(v.z) * hp2[4] + bf16hi(v.z) * hp2[5]
                     + bf16lo(v.w) * hp2[6] + bf16hi(v.w) * hp2[7];
            }
            ((uint16_t*)out)[b * OUTN + j] = f32_to_bf16_rne(acc);
        } else {
            const float4* wo = reinterpret_cast<const float4*>((const float*)Wout + (long)j * HID);
            #pragma unroll
            for (int k = 0; k < 64; k++) {
                float4 v = wo[k];
                const float* hp2 = &h_s[k * 4];
                acc += v.x * hp2[0] + v.y * hp2[1] + v.z * hp2[2] + v.w * hp2[3];
            }
            ((float*)out)[b * OUTN + j] = acc;
        }
    }
}

extern "C" void kernel_launch(void* const* d_in, const int* in_sizes, int n_in,
                              void* d_out, int out_size, void* d_ws, size_t ws_size,
                              hipStream_t stream) {
    const void* x    = d_in[0];  // 8*16*32*112*112
    const void* Wih  = d_in[1];  // 768*784
    const void* Whh  = d_in[2];  // 768*256
    const void* bih  = d_in[3];  // 768
    const void* bhh  = d_in[4];  // 768
    const void* Wout = d_in[5];  // 128*256
    const void* bout = d_in[6];  // 128

    // ws layout (max 1,396,736 B, inside round-2-proven 1.58 MB envelope):
    //   [0 .. 393216)        gi   (live to the end)
    //   [393216 .. 794624)   seq  (dead after last gi pass)
    //   [794624 .. 1396736)  wihT f32 slice, 196*768*4 (dead after last gi)
    //   [393216 .. 1179648)  whhT f32 (reclaims seq + part of wihT slice)
    //   flag at [1396736)
    char* ws = (char*)d_ws;
    float* gi   = (float*)ws;
    float* seq  = (float*)(ws + 393216);
    float* big  = (float*)(ws + 794624);
    float* whhT = (float*)(ws + 393216);
    int*  flagp = (int*)(ws + 1396736);

    detect_kernel<<<1, 256, 0, stream>>>((const uint16_t*)x, flagp);
    pool_kernel<<<2048, 256, 0, stream>>>(x, seq, flagp);

    // W_ih: 4 k-slices of 196, each pack + partial-gi (stream-ordered reuse)
    packT_kernel<768, 784,   0, 196><<<588, 256, 0, stream>>>(Wih, big, flagp);
    gi_kernel<  0, 196><<<128, 768, 0, stream>>>(seq, big, bih, gi, flagp);
    packT_kernel<768, 784, 196, 196><<<588, 256, 0, stream>>>(Wih, big, flagp);
    gi_kernel<196, 196><<<128, 768, 0, stream>>>(seq, big, bih, gi, flagp);
    packT_kernel<768, 784, 392, 196><<<588, 256, 0, stream>>>(Wih, big, flagp);
    gi_kernel<392, 196><<<128, 768, 0, stream>>>(seq, big, bih, gi, flagp);
    packT_kernel<768, 784, 588, 196><<<588, 256, 0, stream>>>(Wih, big, flagp);
    gi_kernel<588, 196><<<128, 768, 0, stream>>>(seq, big, bih, gi, flagp);

    // W_hh -> f32 transposed (overwrites seq + part of big; both dead now)
    packT_kernel<768, 256, 0, 256><<<768, 256, 0, stream>>>(Whh, whhT, flagp);
    gru_kernel<<<8, 768, 0, stream>>>(gi, whhT, bhh, Wout, bout, d_out, flagp);
}